// Round 15
// baseline (148.008 us; speedup 1.0000x reference)
//
#include <hip/hip_runtime.h>
#include <math.h>

typedef __attribute__((ext_vector_type(8))) short short8;
typedef __attribute__((ext_vector_type(4))) short short4v;
typedef __attribute__((ext_vector_type(4))) float f32x4;
typedef __attribute__((ext_vector_type(16))) float f32x16;
typedef _Float16 half8 __attribute__((ext_vector_type(8)));

constexpr int BLOCK = 512;
constexpr int B_ = 4, C_ = 64, N_ = 32768, K_ = 16;
constexpr int P_ = 64;            // points per block -> 192 cols (col = k*64 + p)
constexpr int NCOL = 192;
// wf: 44 f16 hi/lo frags: 20 (L1: 4m x 5ks) + 16 (L2: 2m x 8ks) + 8 (L3: 4m x 2ks),
// each 1024 shorts (hi 512 | lo 512), + 256 folded-bias floats
constexpr int NFRAG = 44;
constexpr int BIAS_OFF = NFRAG * 1024;   // shorts

// x LDS: [9 fr][192 col][8] f16, fr = ci>>3 (ci 64..67 in fr8, 68..71 zero)
// + 8-short broadcast-zero pad at ZOFF (L1 ks=4 upper half)
constexpr int ZOFF = 9 * 1536;           // 13824
constexpr int XSZ  = 13832;              // 27.66 KB
// h1 LDS: [16 fr][192][8] f16 (49.15 KB). h2 aliased onto xa, fr-stride 1544.
constexpr int H2STR = 1544;

__device__ __forceinline__ short f16bits(float v) {
    return (short)__builtin_bit_cast(unsigned short, (_Float16)v);
}

__device__ __forceinline__ f32x16 mm32h(half8 a, half8 b, f32x16 c) {
    return __builtin_amdgcn_mfma_f32_32x32x16_f16(a, b, c, 0, 0, 0);
}
__device__ __forceinline__ f32x4 mm16h(half8 a, half8 b, f32x4 c) {
    return __builtin_amdgcn_mfma_f32_16x16x32_f16(a, b, c, 0, 0, 0);
}

// ---------------- prologue: BN-fold + f16 hi/lo split weights + fold biases ----
__global__ void prep_wfrags(const float* __restrict__ W1, const float* __restrict__ g1,
                            const float* __restrict__ b1, const float* __restrict__ be1,
                            const float* __restrict__ W2, const float* __restrict__ g2,
                            const float* __restrict__ b2, const float* __restrict__ be2,
                            const float* __restrict__ W3, const float* __restrict__ g3,
                            const float* __restrict__ b3, const float* __restrict__ be3,
                            unsigned short* __restrict__ wf)
{
    const int gid = blockIdx.x * 256 + threadIdx.x;
    const float RS = 1.0f / sqrtf(1.0f + 1e-5f);
    const int NT = NFRAG * 64;                   // 2816 fragment lanes
    if (gid < NT) {
        const int f = gid >> 6, l = gid & 63;
        const float *W, *g; int CI, co, kb;
        if (f < 20)      { W = W1; g = g1; CI = 68;
                           co = (f / 5) * 32 + (l & 31);        kb = (f % 5) * 16 + (l >> 5) * 8; }
        else if (f < 36) { W = W2; g = g2; CI = 128;
                           co = ((f - 20) / 8) * 32 + (l & 31); kb = ((f - 20) % 8) * 16 + (l >> 5) * 8; }
        else             { W = W3; g = g3; CI = 64;
                           co = ((f - 36) / 2) * 16 + (l & 15); kb = ((f - 36) % 2) * 32 + (l >> 4) * 8; }
        const float gs = g[co] * RS;
        short8 h8, l8;
#pragma unroll
        for (int j = 0; j < 8; ++j) {
            const int k = kb + j;
            const float w = (k < CI) ? W[(size_t)co * CI + k] * gs : 0.0f;
            _Float16 hf = (_Float16)w;
            h8[j] = (short)__builtin_bit_cast(unsigned short, hf);
            l8[j] = f16bits(w - (float)hf);
        }
        *reinterpret_cast<short8*>(wf + (size_t)f * 1024 + l * 8)       = h8;
        *reinterpret_cast<short8*>(wf + (size_t)f * 1024 + 512 + l * 8) = l8;
    } else if (gid < NT + 256) {
        const int c = gid - NT;
        float* fb = reinterpret_cast<float*>(wf + BIAS_OFF);
        if (c < 128)      fb[c] = b1[c] * (g1[c] * RS) + be1[c];
        else if (c < 192) { const int q = c - 128; fb[c] = b2[q] * (g2[q] * RS) + be2[q]; }
        else              { const int q = c - 192; fb[c] = b3[q] * (g3[q] * RS) + be3[q]; }
    }
}

__device__ __forceinline__ void ldfrag(const unsigned short* __restrict__ wf,
                                       int f, int l, half8 &h, half8 &lo) {
    h  = __builtin_bit_cast(half8,
         *reinterpret_cast<const short8*>(wf + (size_t)f * 1024 + l * 8));
    lo = __builtin_bit_cast(half8,
         *reinterpret_cast<const short8*>(wf + (size_t)f * 1024 + 512 + l * 8));
}

__global__ __launch_bounds__(BLOCK, 6)
void mvp_mfma(const float* __restrict__ src, const float* __restrict__ tgt,
              const float* __restrict__ feat,
              const unsigned short* __restrict__ wf,
              float* __restrict__ out)
{
    __shared__ __align__(16) unsigned short xa[XSZ];        // 27.66 KB (h2 aliases)
    __shared__ __align__(16) unsigned short h1f[16*1536];   // 49.15 KB
    // total 76.8 KB -> 2 blocks/CU

    const int tid = threadIdx.x;
    const int w   = tid >> 6;                    // 8 waves
    const int l   = tid & 63;
    const int b   = blockIdx.x >> 9;             // 512 blocks per batch
    const int n0  = (blockIdx.x & 511) << 6;     // 64 points

    unsigned short* h2f = xa;                    // aliased (x dead after L1)

    // ================= staging (2 groups of 4 outstanding loads) ============
    // LDS zero-pads first (independent of loads)
    if (tid < 192) {                             // zero x fr8 pos 4..7 (ci 68..71)
        const int o = (8*192 + tid) * 8 + 4;
        *reinterpret_cast<short4v*>(&xa[o]) = short4v{0,0,0,0};
    } else if (tid == 192) {                     // zero broadcast pad
        *reinterpret_cast<short8*>(xa + ZOFF) = short8{0,0,0,0,0,0,0,0};
    }
    float rl[6];
    if (tid < 192) {
        const int p = tid & 63, k = tid >> 6, n = n0 + p;
        rl[0] = src[((size_t)(b*3+0)*N_ + n)*K_ + k];
        rl[1] = src[((size_t)(b*3+1)*N_ + n)*K_ + k];
        rl[2] = src[((size_t)(b*3+2)*N_ + n)*K_ + k];
        rl[3] = tgt[(size_t)(b*3+0)*N_ + n];
        rl[4] = tgt[(size_t)(b*3+1)*N_ + n];
        rl[5] = tgt[(size_t)(b*3+2)*N_ + n];
    }
#pragma unroll
    for (int grp = 0; grp < 2; ++grp) {
        float4 pf[4];
#pragma unroll
        for (int it = 0; it < 4; ++it) {
            const int idx = tid + (grp*4 + it) * BLOCK;
            const int c = idx >> 6, p = idx & 63;
            pf[it] = *reinterpret_cast<const float4*>(
                feat + ((size_t)(b*C_ + c) * N_ + (n0 + p)) * K_);
        }
#pragma unroll
        for (int it = 0; it < 4; ++it) {
            const int idx = tid + (grp*4 + it) * BLOCK;
            const int c = idx >> 6, p = idx & 63;
            const float v[3] = {pf[it].x, pf[it].y, pf[it].z};
#pragma unroll
            for (int k = 0; k < 3; ++k)
                xa[((c >> 3)*192 + k*64 + p)*8 + (c & 7)] = (unsigned short)f16bits(v[k]);
        }
    }
    if (tid < 192) {                             // relation -> ci 64..67
        const int p = tid & 63, k = tid >> 6;
        const float d0 = rl[0]-rl[3], d1 = rl[1]-rl[4], d2 = rl[2]-rl[5];
        const float d[4] = {d0, d1, d2, d0*d0 + d1*d1 + d2*d2};
        const int base = (8*192 + k*64 + p)*8;
#pragma unroll
        for (int j = 0; j < 4; ++j)
            xa[base + j] = (unsigned short)f16bits(d[j]);
    }
    __syncthreads();

    const int hi32 = l >> 5, c32 = l & 31;       // 32x32 fragment coords
    const int lq = l >> 4, lr = l & 15, rq = lq << 2;  // 16x16 fragment coords
    const float* fb = reinterpret_cast<const float*>(wf + BIAS_OFF);

    // ================= L1: 68 -> 128 (f16 32x32; wave = m x 3 n-cols) =======
    {
        const int m = w >> 1, nh = w & 1;        // 4m x 2 n-halves
        f32x16 acc[3];
#pragma unroll
        for (int nn = 0; nn < 3; ++nn)
#pragma unroll
            for (int j = 0; j < 16; ++j) acc[nn][j] = 0.0f;

#pragma unroll
        for (int ks = 0; ks < 5; ++ks) {
            half8 ah, al;
            ldfrag(wf, m*5 + ks, l, ah, al);
#pragma unroll
            for (int nn = 0; nn < 3; ++nn) {
                const int col = (nh*3 + nn)*32 + c32;
                const int so = (ks < 4) ? ((ks*2 + hi32)*192 + col)*8
                                        : (hi32 ? ZOFF : (8*192 + col)*8);
                const half8 bh = __builtin_bit_cast(half8,
                    *reinterpret_cast<const short8*>(&xa[so]));
                acc[nn] = mm32h(ah, bh, acc[nn]);
                acc[nn] = mm32h(al, bh, acc[nn]);
            }
        }
        // epilogue -> h1 single f16
#pragma unroll
        for (int nn = 0; nn < 3; ++nn) {
            const int col = (nh*3 + nn)*32 + c32;
#pragma unroll
            for (int g = 0; g < 4; ++g) {
                const int co0 = m*32 + 8*g + 4*hi32;
                const float4 bb = *reinterpret_cast<const float4*>(fb + co0);
                const float bbv[4] = {bb.x, bb.y, bb.z, bb.w};
                short4v h4;
#pragma unroll
                for (int r = 0; r < 4; ++r)
                    h4[r] = f16bits(fmaxf(acc[nn][g*4 + r] + bbv[r], 0.0f));
                const int so = ((m*4 + g)*192 + col)*8 + 4*hi32;
                *reinterpret_cast<short4v*>(&h1f[so]) = h4;
            }
        }
    }
    __syncthreads();

    // ================= L2: 128 -> 64 (f16 32x32; 6 waves x (m, 2 cols)) =====
    if (w < 6) {
        const int m = w / 3, np = w % 3;         // 2m x 3 col-pairs
        f32x16 acc[2];
#pragma unroll
        for (int nn = 0; nn < 2; ++nn)
#pragma unroll
            for (int j = 0; j < 16; ++j) acc[nn][j] = 0.0f;

#pragma unroll
        for (int ks = 0; ks < 8; ++ks) {
            half8 ah, al;
            ldfrag(wf, 20 + m*8 + ks, l, ah, al);
#pragma unroll
            for (int nn = 0; nn < 2; ++nn) {
                const int col = (np*2 + nn)*32 + c32;
                const int so = ((ks*2 + hi32)*192 + col)*8;
                const half8 bh = __builtin_bit_cast(half8,
                    *reinterpret_cast<const short8*>(&h1f[so]));
                acc[nn] = mm32h(ah, bh, acc[nn]);
                acc[nn] = mm32h(al, bh, acc[nn]);
            }
        }
        // h2 (aliased onto xa) with fr-stride 1544, single f16
#pragma unroll
        for (int nn = 0; nn < 2; ++nn) {
            const int col = (np*2 + nn)*32 + c32;
#pragma unroll
            for (int g = 0; g < 4; ++g) {
                const int co0 = m*32 + 8*g + 4*hi32;
                const float4 bb = *reinterpret_cast<const float4*>(fb + 128 + co0);
                const float bbv[4] = {bb.x, bb.y, bb.z, bb.w};
                short4v h4;
#pragma unroll
                for (int r = 0; r < 4; ++r)
                    h4[r] = f16bits(fmaxf(acc[nn][g*4 + r] + bbv[r], 0.0f));
                const int so = (m*4 + g)*H2STR + col*8 + 4*hi32;
                *reinterpret_cast<short4v*>(&h2f[so]) = h4;
            }
        }
    }
    __syncthreads();

    // ================= L3: 64 -> 64 (f16 16x16), relu + k-sum + store =======
    {
        const int m = w >> 1;                    // same m both passes -> frags once
        half8 ah[2], al[2];
#pragma unroll
        for (int ks = 0; ks < 2; ++ks) ldfrag(wf, 36 + m*2 + ks, l, ah[ks], al[ks]);
#pragma unroll
        for (int pass = 0; pass < 2; ++pass) {
            const int pq = (w & 1)*2 + pass;     // point-quarter 0..3
            f32x4 acc3[3] = {f32x4{0,0,0,0}, f32x4{0,0,0,0}, f32x4{0,0,0,0}};
#pragma unroll
            for (int ks = 0; ks < 2; ++ks) {
#pragma unroll
                for (int t = 0; t < 3; ++t) {    // t = neighbor k
                    const int so = (ks*4 + lq)*H2STR + (t*64 + pq*16 + lr)*8;
                    const half8 bh = __builtin_bit_cast(half8,
                        *reinterpret_cast<const short8*>(&h2f[so]));
                    acc3[t] = mm16h(ah[ks], bh, acc3[t]);
                    acc3[t] = mm16h(al[ks], bh, acc3[t]);
                }
            }
            const int co0 = m*16 + rq;
            const float4 bb = *reinterpret_cast<const float4*>(fb + 192 + co0);
            const float bbv[4] = {bb.x, bb.y, bb.z, bb.w};
#pragma unroll
            for (int r = 0; r < 4; ++r) {
                float s = 0.0f;
#pragma unroll
                for (int t = 0; t < 3; ++t) s += fmaxf(acc3[t][r] + bbv[r], 0.0f);
                out[(size_t)(b*64 + co0 + r) * N_ + n0 + pq*16 + lr] = s;
            }
        }
    }
}

extern "C" void kernel_launch(void* const* d_in, const int* in_sizes, int n_in,
                              void* d_out, int out_size, void* d_ws, size_t ws_size,
                              hipStream_t stream) {
    const float* src  = (const float*)d_in[0];
    const float* tgt  = (const float*)d_in[1];
    const float* feat = (const float*)d_in[2];
    const float* W1 = (const float*)d_in[3];
    const float* b1 = (const float*)d_in[4];
    const float* g1 = (const float*)d_in[5];
    const float* be1= (const float*)d_in[6];
    const float* W2 = (const float*)d_in[7];
    const float* b2 = (const float*)d_in[8];
    const float* g2 = (const float*)d_in[9];
    const float* be2= (const float*)d_in[10];
    const float* W3 = (const float*)d_in[11];
    const float* b3 = (const float*)d_in[12];
    const float* g3 = (const float*)d_in[13];
    const float* be3= (const float*)d_in[14];
    float* out = (float*)d_out;
    unsigned short* wfrag = (unsigned short*)d_ws;   // ~91 KB used

    prep_wfrags<<<12, 256, 0, stream>>>(W1, g1, b1, be1, W2, g2, b2, be2,
                                        W3, g3, b3, be3, wfrag);

    const int grid = B_ * (N_ / P_);  // 2048 blocks, 2 resident per CU
    mvp_mfma<<<grid, BLOCK, 0, stream>>>(src, tgt, feat, wfrag, out);
}

// Round 16
// 147.040 us; speedup vs baseline: 1.0066x; 1.0066x over previous
//
#include <hip/hip_runtime.h>
#include <math.h>

typedef __attribute__((ext_vector_type(8))) short short8;
typedef __attribute__((ext_vector_type(4))) short short4v;
typedef __attribute__((ext_vector_type(4))) float f32x4;
typedef __attribute__((ext_vector_type(16))) float f32x16;
typedef _Float16 half8 __attribute__((ext_vector_type(8)));

constexpr int BLOCK = 256;
constexpr int B_ = 4, C_ = 64, N_ = 32768, K_ = 16;
constexpr int P_ = 32;            // points per block -> 96 cols (col = k*32 + p)
// wf: 44 f16 hi/lo frags: 20 (L1: 4m x 5ks) + 16 (L2: 2m x 8ks) + 8 (L3: 4m x 2ks),
// each 1024 shorts (hi 512 | lo 512), + 256 folded-bias floats
constexpr int NFRAG = 44;
constexpr int BIAS_OFF = NFRAG * 1024;   // shorts

// x LDS: [9 fr][96 col][8] f16 single, fr = ci>>3 (ci 64..67 in fr8, 68..71 zero)
// + 8-short broadcast-zero pad at ZOFF (L1 ks=4 upper half)
constexpr int ZOFF = 9 * 768;            // 6912
constexpr int XSZ  = 6920;
// h1 LDS: [16 fr][96][8] f16 single. h2 aliased onto xa, fr-stride 776.
constexpr int H2STR = 776;

__device__ __forceinline__ short f16bits(float v) {
    return (short)__builtin_bit_cast(unsigned short, (_Float16)v);
}

__device__ __forceinline__ f32x16 mm32h(half8 a, half8 b, f32x16 c) {
    return __builtin_amdgcn_mfma_f32_32x32x16_f16(a, b, c, 0, 0, 0);
}
__device__ __forceinline__ f32x4 mm16h(half8 a, half8 b, f32x4 c) {
    return __builtin_amdgcn_mfma_f32_16x16x32_f16(a, b, c, 0, 0, 0);
}

// ---------------- prologue: BN-fold + f16 hi/lo split weights + fold biases ----
__global__ void prep_wfrags(const float* __restrict__ W1, const float* __restrict__ g1,
                            const float* __restrict__ b1, const float* __restrict__ be1,
                            const float* __restrict__ W2, const float* __restrict__ g2,
                            const float* __restrict__ b2, const float* __restrict__ be2,
                            const float* __restrict__ W3, const float* __restrict__ g3,
                            const float* __restrict__ b3, const float* __restrict__ be3,
                            unsigned short* __restrict__ wf)
{
    const int gid = blockIdx.x * 256 + threadIdx.x;
    const float RS = 1.0f / sqrtf(1.0f + 1e-5f);
    const int NT = NFRAG * 64;                   // 2816 fragment lanes
    if (gid < NT) {
        const int f = gid >> 6, l = gid & 63;
        const float *W, *g; int CI, co, kb;
        if (f < 20)      { W = W1; g = g1; CI = 68;
                           co = (f / 5) * 32 + (l & 31);        kb = (f % 5) * 16 + (l >> 5) * 8; }
        else if (f < 36) { W = W2; g = g2; CI = 128;
                           co = ((f - 20) / 8) * 32 + (l & 31); kb = ((f - 20) % 8) * 16 + (l >> 5) * 8; }
        else             { W = W3; g = g3; CI = 64;
                           co = ((f - 36) / 2) * 16 + (l & 15); kb = ((f - 36) % 2) * 32 + (l >> 4) * 8; }
        const float gs = g[co] * RS;
        short8 h8, l8;
#pragma unroll
        for (int j = 0; j < 8; ++j) {
            const int k = kb + j;
            const float w = (k < CI) ? W[(size_t)co * CI + k] * gs : 0.0f;
            _Float16 hf = (_Float16)w;
            h8[j] = (short)__builtin_bit_cast(unsigned short, hf);
            l8[j] = f16bits(w - (float)hf);
        }
        *reinterpret_cast<short8*>(wf + (size_t)f * 1024 + l * 8)       = h8;
        *reinterpret_cast<short8*>(wf + (size_t)f * 1024 + 512 + l * 8) = l8;
    } else if (gid < NT + 256) {
        const int c = gid - NT;
        float* fb = reinterpret_cast<float*>(wf + BIAS_OFF);
        if (c < 128)      fb[c] = b1[c] * (g1[c] * RS) + be1[c];
        else if (c < 192) { const int q = c - 128; fb[c] = b2[q] * (g2[q] * RS) + be2[q]; }
        else              { const int q = c - 192; fb[c] = b3[q] * (g3[q] * RS) + be3[q]; }
    }
}

__device__ __forceinline__ void ldfrag(const unsigned short* __restrict__ wf,
                                       int f, int l, half8 &h, half8 &lo) {
    h  = __builtin_bit_cast(half8,
         *reinterpret_cast<const short8*>(wf + (size_t)f * 1024 + l * 8));
    lo = __builtin_bit_cast(half8,
         *reinterpret_cast<const short8*>(wf + (size_t)f * 1024 + 512 + l * 8));
}

__global__ __launch_bounds__(BLOCK, 4)
void mvp_mfma(const float* __restrict__ src, const float* __restrict__ tgt,
              const float* __restrict__ feat,
              const unsigned short* __restrict__ wf,
              float* __restrict__ out)
{
    __shared__ __align__(16) unsigned short xa[XSZ];       // 13.84 KB (h2 aliases)
    __shared__ __align__(16) unsigned short h1f[16*768];   // 24.58 KB
    // total 38.4 KB; 4 waves/block -> 4 blocks/CU at (256,4), VGPR cap 128

    const int tid = threadIdx.x;
    const int w   = tid >> 6;                    // 4 waves
    const int l   = tid & 63;
    const int b   = blockIdx.x >> 10;            // 1024 blocks per batch
    const int n0  = (blockIdx.x & 1023) << 5;    // 32 points

    unsigned short* h2f = xa;                    // aliased (x dead after L1)

    // ================= staging =================
    if (tid < 96) {                              // zero x fr8 pos 4..7 (ci 68..71)
        const int o = (8*96 + tid) * 8 + 4;
        *reinterpret_cast<short4v*>(&xa[o]) = short4v{0,0,0,0};
    } else if (tid == 96) {                      // zero broadcast pad
        *reinterpret_cast<short8*>(xa + ZOFF) = short8{0,0,0,0,0,0,0,0};
    }
    float rl[6];
    if (tid < 96) {
        const int p = tid & 31, k = tid >> 5, n = n0 + p;
        rl[0] = src[((size_t)(b*3+0)*N_ + n)*K_ + k];
        rl[1] = src[((size_t)(b*3+1)*N_ + n)*K_ + k];
        rl[2] = src[((size_t)(b*3+2)*N_ + n)*K_ + k];
        rl[3] = tgt[(size_t)(b*3+0)*N_ + n];
        rl[4] = tgt[(size_t)(b*3+1)*N_ + n];
        rl[5] = tgt[(size_t)(b*3+2)*N_ + n];
    }
    // feature: 2048 rows over 256 threads = 8 rows/thread, 2 groups of 4 in flight
#pragma unroll
    for (int grp = 0; grp < 2; ++grp) {
        float4 pf[4];
#pragma unroll
        for (int it = 0; it < 4; ++it) {
            const int idx = tid + (grp*4 + it) * BLOCK;
            const int c = idx >> 5, p = idx & 31;
            pf[it] = *reinterpret_cast<const float4*>(
                feat + ((size_t)(b*C_ + c) * N_ + (n0 + p)) * K_);
        }
#pragma unroll
        for (int it = 0; it < 4; ++it) {
            const int idx = tid + (grp*4 + it) * BLOCK;
            const int c = idx >> 5, p = idx & 31;
            const float v[3] = {pf[it].x, pf[it].y, pf[it].z};
#pragma unroll
            for (int k = 0; k < 3; ++k)
                xa[((c >> 3)*96 + k*32 + p)*8 + (c & 7)] = (unsigned short)f16bits(v[k]);
        }
    }
    if (tid < 96) {                              // relation -> ci 64..67
        const int p = tid & 31, k = tid >> 5;
        const float d0 = rl[0]-rl[3], d1 = rl[1]-rl[4], d2 = rl[2]-rl[5];
        const float d[4] = {d0, d1, d2, d0*d0 + d1*d1 + d2*d2};
        const int base = (8*96 + k*32 + p)*8;
#pragma unroll
        for (int j = 0; j < 4; ++j)
            xa[base + j] = (unsigned short)f16bits(d[j]);
    }
    __syncthreads();

    const int hi32 = l >> 5, c32 = l & 31;       // 32x32 fragment coords
    const int lq = l >> 4, lr = l & 15, rq = lq << 2;  // 16x16 fragment coords
    const float* fb = reinterpret_cast<const float*>(wf + BIAS_OFF);

    // ================= L1: 68 -> 128 (f16 32x32, 12 tiles, 3 per wave) ======
    {
#pragma unroll 1
        for (int pass = 0; pass < 3; ++pass) {
            const int t = w + pass*4;            // 0..11
            const int m = t / 3, n = t % 3;
            const int col = n*32 + c32;
            half8 ah[5], al[5];
#pragma unroll
            for (int ks = 0; ks < 5; ++ks) ldfrag(wf, m*5 + ks, l, ah[ks], al[ks]);
            f32x16 acc;
#pragma unroll
            for (int j = 0; j < 16; ++j) acc[j] = 0.0f;
#pragma unroll
            for (int ks = 0; ks < 4; ++ks) {
                const int so = ((ks*2 + hi32)*96 + col)*8;
                const half8 bh = __builtin_bit_cast(half8,
                    *reinterpret_cast<const short8*>(&xa[so]));
                acc = mm32h(ah[ks], bh, acc);
                acc = mm32h(al[ks], bh, acc);
            }
            {   // ks = 4: ci 64..71 real, 72..79 broadcast zero
                const int so = hi32 ? ZOFF : (8*96 + col)*8;
                const half8 bh = __builtin_bit_cast(half8,
                    *reinterpret_cast<const short8*>(&xa[so]));
                acc = mm32h(ah[4], bh, acc);
                acc = mm32h(al[4], bh, acc);
            }
            // epilogue -> h1 single f16
#pragma unroll
            for (int g = 0; g < 4; ++g) {
                const int co0 = m*32 + 8*g + 4*hi32;
                const float4 bb = *reinterpret_cast<const float4*>(fb + co0);
                const float bbv[4] = {bb.x, bb.y, bb.z, bb.w};
                short4v h4;
#pragma unroll
                for (int r = 0; r < 4; ++r)
                    h4[r] = f16bits(fmaxf(acc[g*4 + r] + bbv[r], 0.0f));
                const int so = ((m*4 + g)*96 + col)*8 + 4*hi32;
                *reinterpret_cast<short4v*>(&h1f[so]) = h4;
            }
        }
    }
    __syncthreads();

    // ================= L2: 128 -> 64 (f16 32x32, 6 tiles over 4 waves) ======
    {
        const int nt2 = (w < 2) ? 2 : 1;
#pragma unroll 1
        for (int tt = 0; tt < nt2; ++tt) {
            const int t = w + tt*4;              // 0..5
            const int m = t / 3, n = t % 3;
            const int col = n*32 + c32;
            f32x16 acc;
#pragma unroll
            for (int j = 0; j < 16; ++j) acc[j] = 0.0f;
#pragma unroll
            for (int ks = 0; ks < 8; ++ks) {
                half8 ah, al;
                ldfrag(wf, 20 + m*8 + ks, l, ah, al);
                const int so = ((ks*2 + hi32)*96 + col)*8;
                const half8 bh = __builtin_bit_cast(half8,
                    *reinterpret_cast<const short8*>(&h1f[so]));
                acc = mm32h(ah, bh, acc);
                acc = mm32h(al, bh, acc);
            }
            // h2 (aliased onto xa) with fr-stride 776, single f16
#pragma unroll
            for (int g = 0; g < 4; ++g) {
                const int co0 = m*32 + 8*g + 4*hi32;
                const float4 bb = *reinterpret_cast<const float4*>(fb + 128 + co0);
                const float bbv[4] = {bb.x, bb.y, bb.z, bb.w};
                short4v h4;
#pragma unroll
                for (int r = 0; r < 4; ++r)
                    h4[r] = f16bits(fmaxf(acc[g*4 + r] + bbv[r], 0.0f));
                const int so = (m*4 + g)*H2STR + col*8 + 4*hi32;
                *reinterpret_cast<short4v*>(&h2f[so]) = h4;
            }
        }
    }
    __syncthreads();

    // ================= L3: 64 -> 64 (f16 16x16), relu + k-sum + store =======
    {
        const int m = w;                         // frags loaded once per wave
        half8 ah[2], al[2];
#pragma unroll
        for (int ks = 0; ks < 2; ++ks) ldfrag(wf, 36 + m*2 + ks, l, ah[ks], al[ks]);
#pragma unroll
        for (int hh = 0; hh < 2; ++hh) {
            f32x4 acc3[3] = {f32x4{0,0,0,0}, f32x4{0,0,0,0}, f32x4{0,0,0,0}};
#pragma unroll
            for (int ks = 0; ks < 2; ++ks) {
#pragma unroll
                for (int t = 0; t < 3; ++t) {    // t = neighbor k
                    const int so = (ks*4 + lq)*H2STR + (t*32 + hh*16 + lr)*8;
                    const half8 bh = __builtin_bit_cast(half8,
                        *reinterpret_cast<const short8*>(&h2f[so]));
                    acc3[t] = mm16h(ah[ks], bh, acc3[t]);
                    acc3[t] = mm16h(al[ks], bh, acc3[t]);
                }
            }
            const int co0 = m*16 + rq;
            const float4 bb = *reinterpret_cast<const float4*>(fb + 192 + co0);
            const float bbv[4] = {bb.x, bb.y, bb.z, bb.w};
#pragma unroll
            for (int r = 0; r < 4; ++r) {
                float s = 0.0f;
#pragma unroll
                for (int t = 0; t < 3; ++t) s += fmaxf(acc3[t][r] + bbv[r], 0.0f);
                out[(size_t)(b*64 + co0 + r) * N_ + n0 + hh*16 + lr] = s;
            }
        }
    }
}

extern "C" void kernel_launch(void* const* d_in, const int* in_sizes, int n_in,
                              void* d_out, int out_size, void* d_ws, size_t ws_size,
                              hipStream_t stream) {
    const float* src  = (const float*)d_in[0];
    const float* tgt  = (const float*)d_in[1];
    const float* feat = (const float*)d_in[2];
    const float* W1 = (const float*)d_in[3];
    const float* b1 = (const float*)d_in[4];
    const float* g1 = (const float*)d_in[5];
    const float* be1= (const float*)d_in[6];
    const float* W2 = (const float*)d_in[7];
    const float* b2 = (const float*)d_in[8];
    const float* g2 = (const float*)d_in[9];
    const float* be2= (const float*)d_in[10];
    const float* W3 = (const float*)d_in[11];
    const float* b3 = (const float*)d_in[12];
    const float* g3 = (const float*)d_in[13];
    const float* be3= (const float*)d_in[14];
    float* out = (float*)d_out;
    unsigned short* wfrag = (unsigned short*)d_ws;   // ~91 KB used

    prep_wfrags<<<12, 256, 0, stream>>>(W1, g1, b1, be1, W2, g2, b2, be2,
                                        W3, g3, b3, be3, wfrag);

    const int grid = B_ * (N_ / P_);  // 4096 blocks, 4 resident per CU
    mvp_mfma<<<grid, BLOCK, 0, stream>>>(src, tgt, feat, wfrag, out);
}

// Round 17
// 137.597 us; speedup vs baseline: 1.0757x; 1.0686x over previous
//
#include <hip/hip_runtime.h>
#include <math.h>

typedef __attribute__((ext_vector_type(8))) short short8;
typedef __attribute__((ext_vector_type(4))) short short4v;
typedef __attribute__((ext_vector_type(4))) float f32x4;
typedef __attribute__((ext_vector_type(16))) float f32x16;
typedef _Float16 half8 __attribute__((ext_vector_type(8)));

constexpr int BLOCK = 512;
constexpr int B_ = 4, C_ = 64, N_ = 32768, K_ = 16;
constexpr int P_ = 32;            // points per block -> 96 cols (col = k*32 + p)
// wf: 44 single-f16 frags: 20 (L1: 4m x 5ks) + 16 (L2: 2m x 8ks) + 8 (L3: 4m x 2ks),
// each 512 shorts, + 256 folded-bias floats
constexpr int NFRAG = 44;
constexpr int BIAS_OFF = NFRAG * 512;    // shorts

// x LDS: [9 fr][96 col][8] f16 single, fr = ci>>3 (ci 64..67 in fr8, 68..71 zero)
// + 8-short broadcast-zero pad at ZOFF (L1 ks=4 upper half)
constexpr int ZOFF = 9 * 768;            // 6912
constexpr int XSZ  = 6920;
// h1 LDS: [16 fr][96][8] f16 single. h2 aliased onto xa, fr-stride 776.
constexpr int H2STR = 776;

__device__ __forceinline__ short f16bits(float v) {
    return (short)__builtin_bit_cast(unsigned short, (_Float16)v);
}

__device__ __forceinline__ f32x16 mm32h(half8 a, half8 b, f32x16 c) {
    return __builtin_amdgcn_mfma_f32_32x32x16_f16(a, b, c, 0, 0, 0);
}
__device__ __forceinline__ f32x4 mm16h(half8 a, half8 b, f32x4 c) {
    return __builtin_amdgcn_mfma_f32_16x16x32_f16(a, b, c, 0, 0, 0);
}

// ---------------- prologue: BN-fold + single-f16 weights + fold biases ------
__global__ void prep_wfrags(const float* __restrict__ W1, const float* __restrict__ g1,
                            const float* __restrict__ b1, const float* __restrict__ be1,
                            const float* __restrict__ W2, const float* __restrict__ g2,
                            const float* __restrict__ b2, const float* __restrict__ be2,
                            const float* __restrict__ W3, const float* __restrict__ g3,
                            const float* __restrict__ b3, const float* __restrict__ be3,
                            unsigned short* __restrict__ wf)
{
    const int gid = blockIdx.x * 256 + threadIdx.x;
    const float RS = 1.0f / sqrtf(1.0f + 1e-5f);
    const int NT = NFRAG * 64;                   // 2816 fragment lanes
    if (gid < NT) {
        const int f = gid >> 6, l = gid & 63;
        const float *W, *g; int CI, co, kb;
        if (f < 20)      { W = W1; g = g1; CI = 68;
                           co = (f / 5) * 32 + (l & 31);        kb = (f % 5) * 16 + (l >> 5) * 8; }
        else if (f < 36) { W = W2; g = g2; CI = 128;
                           co = ((f - 20) / 8) * 32 + (l & 31); kb = ((f - 20) % 8) * 16 + (l >> 5) * 8; }
        else             { W = W3; g = g3; CI = 64;
                           co = ((f - 36) / 2) * 16 + (l & 15); kb = ((f - 36) % 2) * 32 + (l >> 4) * 8; }
        const float gs = g[co] * RS;
        short8 h8;
#pragma unroll
        for (int j = 0; j < 8; ++j) {
            const int k = kb + j;
            const float w = (k < CI) ? W[(size_t)co * CI + k] * gs : 0.0f;
            h8[j] = f16bits(w);
        }
        *reinterpret_cast<short8*>(wf + (size_t)f * 512 + l * 8) = h8;
    } else if (gid < NT + 256) {
        const int c = gid - NT;
        float* fb = reinterpret_cast<float*>(wf + BIAS_OFF);
        if (c < 128)      fb[c] = b1[c] * (g1[c] * RS) + be1[c];
        else if (c < 192) { const int q = c - 128; fb[c] = b2[q] * (g2[q] * RS) + be2[q]; }
        else              { const int q = c - 192; fb[c] = b3[q] * (g3[q] * RS) + be3[q]; }
    }
}

__device__ __forceinline__ half8 ldfrag(const unsigned short* __restrict__ wf,
                                        int f, int l) {
    return __builtin_bit_cast(half8,
        *reinterpret_cast<const short8*>(wf + (size_t)f * 512 + l * 8));
}

__global__ __launch_bounds__(BLOCK, 8)
void mvp_mfma(const float* __restrict__ src, const float* __restrict__ tgt,
              const float* __restrict__ feat,
              const unsigned short* __restrict__ wf,
              float* __restrict__ out)
{
    __shared__ __align__(16) unsigned short xa[XSZ];       // 13.84 KB (h2 aliases)
    __shared__ __align__(16) unsigned short h1f[16*768];   // 24.58 KB
    // total 38.4 KB -> 4 blocks/CU at (512,8) with VGPR <= 64

    const int tid = threadIdx.x;
    const int w   = tid >> 6;                    // 8 waves
    const int l   = tid & 63;
    const int b   = blockIdx.x >> 10;            // 1024 blocks per batch
    const int n0  = (blockIdx.x & 1023) << 5;    // 32 points

    unsigned short* h2f = xa;                    // aliased (x dead after L1)

    // ================= staging: all loads issued up front ===================
    float4 pf[4];
#pragma unroll
    for (int it = 0; it < 4; ++it) {
        const int idx = tid + it * BLOCK;
        const int c = idx >> 5, p = idx & 31;
        pf[it] = *reinterpret_cast<const float4*>(
            feat + ((size_t)(b*C_ + c) * N_ + (n0 + p)) * K_);
    }
    float rl[6];
    if (tid < 96) {
        const int p = tid & 31, k = tid >> 5, n = n0 + p;
        rl[0] = src[((size_t)(b*3+0)*N_ + n)*K_ + k];
        rl[1] = src[((size_t)(b*3+1)*N_ + n)*K_ + k];
        rl[2] = src[((size_t)(b*3+2)*N_ + n)*K_ + k];
        rl[3] = tgt[(size_t)(b*3+0)*N_ + n];
        rl[4] = tgt[(size_t)(b*3+1)*N_ + n];
        rl[5] = tgt[(size_t)(b*3+2)*N_ + n];
    }

    // LDS zero-pads while loads are in flight
    if (tid < 96) {                              // zero x fr8 pos 4..7 (ci 68..71)
        const int o = (8*96 + tid) * 8 + 4;
        *reinterpret_cast<short4v*>(&xa[o]) = short4v{0,0,0,0};
    } else if (tid == 96) {                      // zero broadcast pad
        *reinterpret_cast<short8*>(xa + ZOFF) = short8{0,0,0,0,0,0,0,0};
    }

    // convert + write feature -> ci 0..63: fr = c>>3, pos = c&7 (f16 single)
#pragma unroll
    for (int it = 0; it < 4; ++it) {
        const int idx = tid + it * BLOCK;
        const int c = idx >> 5, p = idx & 31;
        const float v[3] = {pf[it].x, pf[it].y, pf[it].z};
#pragma unroll
        for (int k = 0; k < 3; ++k)
            xa[((c >> 3)*96 + k*32 + p)*8 + (c & 7)] = (unsigned short)f16bits(v[k]);
    }
    // relation -> ci 64..67 (fr 8 pos 0..3)
    if (tid < 96) {
        const int p = tid & 31, k = tid >> 5;
        const float d0 = rl[0]-rl[3], d1 = rl[1]-rl[4], d2 = rl[2]-rl[5];
        const float d[4] = {d0, d1, d2, d0*d0 + d1*d1 + d2*d2};
        const int base = (8*96 + k*32 + p)*8;
#pragma unroll
        for (int j = 0; j < 4; ++j)
            xa[base + j] = (unsigned short)f16bits(d[j]);
    }
    __syncthreads();

    const int hi32 = l >> 5, c32 = l & 31;       // 32x32 fragment coords
    const int lq = l >> 4, lr = l & 15, rq = lq << 2;  // 16x16 fragment coords
    const float* fb = reinterpret_cast<const float*>(wf + BIAS_OFF);

    // ================= L1: 68 -> 128 (f16 32x32, 12 tiles) ==================
    {
        const int npass = (w < 4) ? 2 : 1;
        for (int pass = 0; pass < npass; ++pass) {
            const int t = pass ? (8 + w) : w;
            const int m = t / 3, n = t % 3;
            const int col = n*32 + c32;
            half8 ah[5];
#pragma unroll
            for (int ks = 0; ks < 5; ++ks) ah[ks] = ldfrag(wf, m*5 + ks, l);
            f32x16 acc;
#pragma unroll
            for (int j = 0; j < 16; ++j) acc[j] = 0.0f;
#pragma unroll
            for (int ks = 0; ks < 4; ++ks) {
                const int so = ((ks*2 + hi32)*96 + col)*8;
                const half8 bh = __builtin_bit_cast(half8,
                    *reinterpret_cast<const short8*>(&xa[so]));
                acc = mm32h(ah[ks], bh, acc);
            }
            {   // ks = 4: ci 64..71 real, 72..79 broadcast zero
                const int so = hi32 ? ZOFF : (8*96 + col)*8;
                const half8 bh = __builtin_bit_cast(half8,
                    *reinterpret_cast<const short8*>(&xa[so]));
                acc = mm32h(ah[4], bh, acc);
            }
            // epilogue -> h1 single f16
#pragma unroll
            for (int g = 0; g < 4; ++g) {
                const int co0 = m*32 + 8*g + 4*hi32;
                const float4 bb = *reinterpret_cast<const float4*>(fb + co0);
                const float bbv[4] = {bb.x, bb.y, bb.z, bb.w};
                short4v h4;
#pragma unroll
                for (int r = 0; r < 4; ++r)
                    h4[r] = f16bits(fmaxf(acc[g*4 + r] + bbv[r], 0.0f));
                const int so = ((m*4 + g)*96 + col)*8 + 4*hi32;
                *reinterpret_cast<short4v*>(&h1f[so]) = h4;
            }
        }
    }
    __syncthreads();

    // ================= L2: 128 -> 64 (f16 32x32, 6 tiles, waves 0..5) =======
    if (w < 6) {
        const int m = w / 3, n = w % 3;
        const int col = n*32 + c32;
        f32x16 acc;
#pragma unroll
        for (int j = 0; j < 16; ++j) acc[j] = 0.0f;
#pragma unroll
        for (int ks = 0; ks < 8; ++ks) {
            const half8 ah = ldfrag(wf, 20 + m*8 + ks, l);
            const int so = ((ks*2 + hi32)*96 + col)*8;
            const half8 bh = __builtin_bit_cast(half8,
                *reinterpret_cast<const short8*>(&h1f[so]));
            acc = mm32h(ah, bh, acc);
        }
        // h2 (aliased onto xa) with fr-stride 776, single f16
#pragma unroll
        for (int g = 0; g < 4; ++g) {
            const int co0 = m*32 + 8*g + 4*hi32;
            const float4 bb = *reinterpret_cast<const float4*>(fb + 128 + co0);
            const float bbv[4] = {bb.x, bb.y, bb.z, bb.w};
            short4v h4;
#pragma unroll
            for (int r = 0; r < 4; ++r)
                h4[r] = f16bits(fmaxf(acc[g*4 + r] + bbv[r], 0.0f));
            const int so = (m*4 + g)*H2STR + col*8 + 4*hi32;
            *reinterpret_cast<short4v*>(&h2f[so]) = h4;
        }
    }
    __syncthreads();

    // ================= L3: 64 -> 64 (f16 16x16), relu + neighbor-sum + store =
    {
        const int m = w >> 1, hh = w & 1;
        half8 ah[2];
#pragma unroll
        for (int ks = 0; ks < 2; ++ks) ah[ks] = ldfrag(wf, 36 + m*2 + ks, l);
        f32x4 acc3[3] = {f32x4{0,0,0,0}, f32x4{0,0,0,0}, f32x4{0,0,0,0}};
#pragma unroll
        for (int ks = 0; ks < 2; ++ks) {
#pragma unroll
            for (int t = 0; t < 3; ++t) {          // t = neighbor k
                const int so = (ks*4 + lq)*H2STR + (t*32 + hh*16 + lr)*8;
                const half8 bh = __builtin_bit_cast(half8,
                    *reinterpret_cast<const short8*>(&h2f[so]));
                acc3[t] = mm16h(ah[ks], bh, acc3[t]);
            }
        }
        const int co0 = m*16 + rq;
        const float4 bb = *reinterpret_cast<const float4*>(fb + 192 + co0);
        const float bbv[4] = {bb.x, bb.y, bb.z, bb.w};
#pragma unroll
        for (int r = 0; r < 4; ++r) {
            float s = 0.0f;
#pragma unroll
            for (int t = 0; t < 3; ++t) s += fmaxf(acc3[t][r] + bbv[r], 0.0f);
            out[(size_t)(b*64 + co0 + r) * N_ + n0 + hh*16 + lr] = s;
        }
    }
}

extern "C" void kernel_launch(void* const* d_in, const int* in_sizes, int n_in,
                              void* d_out, int out_size, void* d_ws, size_t ws_size,
                              hipStream_t stream) {
    const float* src  = (const float*)d_in[0];
    const float* tgt  = (const float*)d_in[1];
    const float* feat = (const float*)d_in[2];
    const float* W1 = (const float*)d_in[3];
    const float* b1 = (const float*)d_in[4];
    const float* g1 = (const float*)d_in[5];
    const float* be1= (const float*)d_in[6];
    const float* W2 = (const float*)d_in[7];
    const float* b2 = (const float*)d_in[8];
    const float* g2 = (const float*)d_in[9];
    const float* be2= (const float*)d_in[10];
    const float* W3 = (const float*)d_in[11];
    const float* b3 = (const float*)d_in[12];
    const float* g3 = (const float*)d_in[13];
    const float* be3= (const float*)d_in[14];
    float* out = (float*)d_out;
    unsigned short* wfrag = (unsigned short*)d_ws;   // ~46 KB used

    prep_wfrags<<<12, 256, 0, stream>>>(W1, g1, b1, be1, W2, g2, b2, be2,
                                        W3, g3, b3, be3, wfrag);

    const int grid = B_ * (N_ / P_);  // 4096 blocks, 4 resident per CU
    mvp_mfma<<<grid, BLOCK, 0, stream>>>(src, tgt, feat, wfrag, out);
}